// Round 1
// baseline (1180.566 us; speedup 1.0000x reference)
//
#include <hip/hip_runtime.h>

// Time2Vec: out[r][0:1024]   = w*x[r][:] + p                  (linear half)
//           out[r][1024:2048]= sw*sin(z)+cw*cos(z), z = xW+P  (periodic half)
//
// Strategy: split-bf16 3-term GEMM (x_hi*W_hi + x_hi*W_lo + x_lo*W_hi) via
// 16x16x32 bf16 MFMA, m97-style 128x128 tile with global_load_lds staging.

typedef __attribute__((ext_vector_type(4))) float    f32x4;
typedef __attribute__((ext_vector_type(8))) short    short8;
typedef __attribute__((ext_vector_type(4))) unsigned short u16x4;

#define IN_F   1024
#define BATCH  65536
#define BM     128
#define BN     128
#define BK     32

// ---- bf16 helpers (RNE, bit-level; inputs are finite normals) ----
__device__ __forceinline__ unsigned short f2bf(float f) {
    unsigned u = __float_as_uint(f);
    u += 0x7fffu + ((u >> 16) & 1u);
    return (unsigned short)(u >> 16);
}
__device__ __forceinline__ float bf2f(unsigned short b) {
    return __uint_as_float(((unsigned)b) << 16);
}

// ---- async global->LDS, 16B per lane (wave-uniform LDS base + lane*16) ----
__device__ __forceinline__ void async_copy16(const void* g, void* l) {
    __builtin_amdgcn_global_load_lds(
        (const __attribute__((address_space(1))) void*)g,
        (__attribute__((address_space(3))) void*)l, 16, 0, 0);
}

// ============================================================
// Prep 1: read x, write linear half of out, write x_hi/x_lo bf16
// grid 65536 x 256, 4 elems/thread
// ============================================================
__global__ __launch_bounds__(256) void prep_x_kernel(
    const f32x4* __restrict__ x4, const float* __restrict__ wp,
    const float* __restrict__ pp, float* __restrict__ out,
    u16x4* __restrict__ Xhi, u16x4* __restrict__ Xlo)
{
    unsigned idx = blockIdx.x * 256u + threadIdx.x;   // 0 .. 16777215
    f32x4 v = x4[idx];
    float w = wp[0], p = pp[0];
    unsigned e = idx * 4u;
    unsigned r = e >> 10, cc = e & 1023u;
    f32x4 o = v * w + p;
    *(f32x4*)(out + (size_t)r * 2048 + cc) = o;
    u16x4 h, l;
#pragma unroll
    for (int i = 0; i < 4; ++i) {
        unsigned short hh = f2bf(v[i]);
        h[i] = hh;
        l[i] = f2bf(v[i] - bf2f(hh));
    }
    Xhi[idx] = h;
    Xlo[idx] = l;
}

// ============================================================
// Prep 2: W[k][n] fp32 -> Whi_t[n][k], Wlo_t[n][k] bf16 (transpose + split)
// grid (32,32), block (32,8)
// ============================================================
__global__ __launch_bounds__(256) void prep_w_kernel(
    const float* __restrict__ W,
    unsigned short* __restrict__ Whi, unsigned short* __restrict__ Wlo)
{
    __shared__ float t[32][33];
    int tx = threadIdx.x, ty = threadIdx.y;
    int n0 = blockIdx.x * 32, k0 = blockIdx.y * 32;
#pragma unroll
    for (int i = 0; i < 4; ++i)
        t[ty + i * 8][tx] = W[(size_t)(k0 + ty + i * 8) * IN_F + n0 + tx];
    __syncthreads();
#pragma unroll
    for (int i = 0; i < 4; ++i) {
        float v = t[tx][ty + i * 8];
        int n = n0 + ty + i * 8, k = k0 + tx;
        unsigned short h = f2bf(v);
        Whi[(size_t)n * IN_F + k] = h;
        Wlo[(size_t)n * IN_F + k] = f2bf(v - bf2f(h));
    }
}

// ============================================================
// GEMM: z = Xhi*Whi + Xhi*Wlo + Xlo*Whi (K'=3072), epilogue sin/cos
// 128x128 tile, BK=32, 256 threads (4 waves, 2x2), 16x16x32 bf16 MFMA
// ============================================================
__global__ __launch_bounds__(256, 2) void gemm_kernel(
    const unsigned short* __restrict__ Xhi, const unsigned short* __restrict__ Xlo,
    const unsigned short* __restrict__ Whi, const unsigned short* __restrict__ Wlo,
    const float* __restrict__ P, const float* __restrict__ swp,
    const float* __restrict__ cwp, float* __restrict__ out)
{
    __shared__ unsigned short As[BM * BK];   // 8 KB, [row][k] row-major, unpadded
    __shared__ unsigned short Bs[BN * BK];   // 8 KB, [n][k]   row-major, unpadded

    const int tid  = threadIdx.x;
    const int lane = tid & 63;
    const int wave = tid >> 6;

    // XCD-friendly swizzle: the 8 n-blocks of one m-band share bid%8 (same XCD
    // under round-robin) so the A-band stays L2-resident across its 8 readers.
    int bid = blockIdx.x;                 // 0..4095
    int c = bid & 7, s = bid >> 3;
    int m_blk = (s >> 3) * 8 + c;         // 0..511
    int n_blk = s & 7;                    // 0..7
    const int m0 = m_blk * BM;
    const int n0 = n_blk * BN;

    // staging geometry: each lane loads 16B = 8 bf16 (quarter of a 32-elem row)
    const int srow = lane >> 2;           // 0..15
    const int scol = (lane & 3) * 8;      // 0,8,16,24

    // fragment geometry (A: m=lane&15, k=(lane>>4)*8+j ; B: n=lane&15, same k)
    const int fr = lane & 15;
    const int fk = (lane >> 4) * 8;
    const int wm = wave & 1;              // wave row (0..1) -> 64 rows
    const int wn = wave >> 1;             // wave col (0..1) -> 64 cols

    f32x4 acc[4][4] = {};

    for (int kt = 0; kt < 96; ++kt) {
        const int part = kt >> 5;                 // 0,1,2
        const int k0   = (kt & 31) * BK;
        const unsigned short* Ap = (part == 2) ? Xlo : Xhi;
        const unsigned short* Bp = (part == 1) ? Wlo : Whi;

        __syncthreads();   // previous iter's ds_reads done before overwrite
#pragma unroll
        for (int cc = 0; cc < 2; ++cc) {
            int chunk = wave * 2 + cc;            // 0..7 -> 16 rows each
            const unsigned short* ga =
                Ap + (size_t)(m0 + chunk * 16 + srow) * IN_F + k0 + scol;
            async_copy16(ga, (char*)As + chunk * 1024 + lane * 16);
            const unsigned short* gb =
                Bp + (size_t)(n0 + chunk * 16 + srow) * IN_F + k0 + scol;
            async_copy16(gb, (char*)Bs + chunk * 1024 + lane * 16);
        }
        __syncthreads();   // vmcnt(0) drain -> staging visible

        short8 a[4], b[4];
#pragma unroll
        for (int i = 0; i < 4; ++i) {
            a[i] = *(const short8*)&As[(wm * 64 + i * 16 + fr) * BK + fk];
            b[i] = *(const short8*)&Bs[(wn * 64 + i * 16 + fr) * BK + fk];
        }
#pragma unroll
        for (int i = 0; i < 4; ++i)
#pragma unroll
            for (int j = 0; j < 4; ++j)
                acc[i][j] = __builtin_amdgcn_mfma_f32_16x16x32_bf16(
                    a[i], b[j], acc[i][j], 0, 0, 0);
    }

    // epilogue: z = acc + P[col]; out_periodic = sw*sin(z) + cw*cos(z)
    const float sw = swp[0], cw = cwp[0];
#pragma unroll
    for (int j = 0; j < 4; ++j) {
        const int colg = n0 + wn * 64 + j * 16 + (lane & 15);
        const float pcol = P[colg];
#pragma unroll
        for (int i = 0; i < 4; ++i) {
#pragma unroll
            for (int r = 0; r < 4; ++r) {
                int rowg = m0 + wm * 64 + i * 16 + (lane >> 4) * 4 + r;
                float z = acc[i][j][r] + pcol;
                float val = sw * __sinf(z) + cw * __cosf(z);
                out[(size_t)rowg * 2048 + 1024 + colg] = val;
            }
        }
    }
}

// ============================================================
// Fallback (only if workspace too small): naive but correct
// ============================================================
__global__ __launch_bounds__(256) void naive_kernel(
    const float* __restrict__ x, const float* __restrict__ W,
    const float* __restrict__ P, const float* __restrict__ wp,
    const float* __restrict__ pp, const float* __restrict__ swp,
    const float* __restrict__ cwp, float* __restrict__ out)
{
    size_t idx = (size_t)blockIdx.x * 256 + threadIdx.x;
    if (idx >= (size_t)BATCH * IN_F) return;
    size_t r = idx >> 10;
    int n = (int)(idx & 1023);
    float acc = 0.f;
    for (int k = 0; k < IN_F; ++k)
        acc = fmaf(x[r * IN_F + k], W[(size_t)k * IN_F + n], acc);
    float z = acc + P[n];
    out[r * 2048 + n] = wp[0] * x[r * IN_F + n] + pp[0];
    out[r * 2048 + 1024 + n] = swp[0] * __sinf(z) + cwp[0] * __cosf(z);
}

extern "C" void kernel_launch(void* const* d_in, const int* in_sizes, int n_in,
                              void* d_out, int out_size, void* d_ws, size_t ws_size,
                              hipStream_t stream)
{
    const float* x   = (const float*)d_in[0];
    const float* W   = (const float*)d_in[1];
    const float* P   = (const float*)d_in[2];
    const float* w   = (const float*)d_in[3];
    const float* p   = (const float*)d_in[4];
    const float* swv = (const float*)d_in[5];
    const float* cwv = (const float*)d_in[6];
    float* out = (float*)d_out;

    const size_t xElems = (size_t)BATCH * IN_F;          // 67,108,864
    const size_t wElems = (size_t)IN_F * IN_F;           // 1,048,576
    const size_t need   = xElems * 2 * 2 + wElems * 2 * 2;  // ~260 MB

    if (ws_size >= need) {
        unsigned short* Xhi = (unsigned short*)d_ws;
        unsigned short* Xlo = Xhi + xElems;
        unsigned short* Whi = Xlo + xElems;
        unsigned short* Wlo = Whi + wElems;

        prep_x_kernel<<<65536, 256, 0, stream>>>(
            (const f32x4*)x, w, p, out, (u16x4*)Xhi, (u16x4*)Xlo);
        prep_w_kernel<<<dim3(32, 32), dim3(32, 8), 0, stream>>>(W, Whi, Wlo);
        gemm_kernel<<<4096, 256, 0, stream>>>(Xhi, Xlo, Whi, Wlo, P, swv, cwv, out);
    } else {
        naive_kernel<<<(unsigned)((xElems + 255) / 256), 256, 0, stream>>>(
            x, W, P, w, p, swv, cwv, out);
    }
}